// Round 1
// baseline (1623.916 us; speedup 1.0000x reference)
//
#include <hip/hip_runtime.h>

#define Nn 50000
#define Dd 64
#define Ee 800000
#define Ll 3
#define Rr 2
#define Gg 128
#define Cc 10

// ---------------- scatter: per-edge relation-masked aggregation -------------
// wave per edge, lane = feature. agg layout: [R][N][D]
__global__ __launch_bounds__(256) void k_scatter(
    const float* __restrict__ h, const int* __restrict__ src,
    const int* __restrict__ dst, const int* __restrict__ et,
    float* __restrict__ agg)
{
  int e = blockIdx.x * 4 + (threadIdx.x >> 6);
  if (e >= Ee) return;
  int lane = threadIdx.x & 63;
  int s = src[e];
  int d = dst[e];
  int t = et[e];
  float v = h[(size_t)s * Dd + lane];
  atomicAdd(&agg[((size_t)t * Nn + (size_t)d) * Dd + lane], v);
}

// ---------------- fused per-layer update -----------------------------------
// x_new = h@selfW + selfb + sum_r relu(((1+eps_r)h + agg_r)@W1_r + b1_r)@W2_r + b2_r
// Block = 512 thr = 8 waves, wave per node, weights staged in LDS.
__global__ __launch_bounds__(512) void k_update(
    const float* __restrict__ h, const float* __restrict__ agg,
    const float* __restrict__ selfW, const float* __restrict__ selfb,
    const float* __restrict__ eps,
    const float* __restrict__ W1, const float* __restrict__ b1,
    const float* __restrict__ W2, const float* __restrict__ b2,
    float* __restrict__ hn, int l)
{
  __shared__ float sW[5][Dd * Dd];   // 80 KB
  __shared__ float sb[5][Dd];

  const float* gW[5] = {
      selfW + (size_t)l * Dd * Dd,
      W1 + ((size_t)l * Rr + 0) * Dd * Dd,
      W2 + ((size_t)l * Rr + 0) * Dd * Dd,
      W1 + ((size_t)l * Rr + 1) * Dd * Dd,
      W2 + ((size_t)l * Rr + 1) * Dd * Dd};
  const float* gb[5] = {
      selfb + (size_t)l * Dd,
      b1 + ((size_t)l * Rr + 0) * Dd,
      b2 + ((size_t)l * Rr + 0) * Dd,
      b1 + ((size_t)l * Rr + 1) * Dd,
      b2 + ((size_t)l * Rr + 1) * Dd};
#pragma unroll
  for (int m = 0; m < 5; ++m) {
    for (int i = threadIdx.x; i < Dd * Dd; i += 512) sW[m][i] = gW[m][i];
    if (threadIdx.x < Dd) sb[m][threadIdx.x] = gb[m][threadIdx.x];
  }
  __syncthreads();

  float e0 = 1.0f + eps[l * Rr + 0];
  float e1 = 1.0f + eps[l * Rr + 1];
  int wave = threadIdx.x >> 6;
  int lane = threadIdx.x & 63;

  for (int base = blockIdx.x * 8; base < Nn; base += gridDim.x * 8) {
    int n = base + wave;           // wave-uniform predicate, no barrier in loop
    if (n >= Nn) continue;
    float hv = h[(size_t)n * Dd + lane];

    // self loop
    float xn = sb[0][lane];
#pragma unroll
    for (int k = 0; k < Dd; ++k)
      xn += __shfl(hv, k, 64) * sW[0][k * Dd + lane];

#pragma unroll
    for (int r = 0; r < Rr; ++r) {
      float er = (r == 0) ? e0 : e1;
      float zv = er * hv + agg[((size_t)r * Nn + (size_t)n) * Dd + lane];
      float t = sb[1 + 2 * r][lane];
#pragma unroll
      for (int k = 0; k < Dd; ++k)
        t += __shfl(zv, k, 64) * sW[1 + 2 * r][k * Dd + lane];
      t = fmaxf(t, 0.0f);
      float u = sb[2 + 2 * r][lane];
#pragma unroll
      for (int k = 0; k < Dd; ++k)
        u += __shfl(t, k, 64) * sW[2 + 2 * r][k * Dd + lane];
      xn += u;
    }
    hn[(size_t)n * Dd + lane] = xn;
  }
}

// ---------------- global mean pool (atomic accumulate) ----------------------
__global__ __launch_bounds__(256) void k_pool(
    const float* __restrict__ h, const int* __restrict__ batch,
    float* __restrict__ sums, float* __restrict__ cnts)
{
  int n = blockIdx.x * 4 + (threadIdx.x >> 6);
  if (n >= Nn) return;
  int lane = threadIdx.x & 63;
  int g = batch[n];
  atomicAdd(&sums[(size_t)g * Dd + lane], h[(size_t)n * Dd + lane]);
  if (lane == 0) atomicAdd(&cnts[g], 1.0f);
}

// ---------------- head: pooled -> relu(lin1) -> lin2 ------------------------
__global__ __launch_bounds__(256) void k_head(
    const float* __restrict__ sums, const float* __restrict__ cnts,
    const float* __restrict__ l1W, const float* __restrict__ l1b,
    const float* __restrict__ l2W, const float* __restrict__ l2b,
    float* __restrict__ out)
{
  int wave = threadIdx.x >> 6;
  int lane = threadIdx.x & 63;
  for (int g = wave; g < Gg; g += 4) {
    float p = sums[(size_t)g * Dd + lane] / fmaxf(cnts[g], 1.0f);
    float t = l1b[lane];
#pragma unroll
    for (int k = 0; k < Dd; ++k)
      t += __shfl(p, k, 64) * l1W[k * Dd + lane];
    t = fmaxf(t, 0.0f);
    float o = (lane < Cc) ? l2b[lane] : 0.0f;
#pragma unroll
    for (int k = 0; k < Dd; ++k) {
      float w = (lane < Cc) ? l2W[k * Cc + lane] : 0.0f;
      o += __shfl(t, k, 64) * w;
    }
    if (lane < Cc) out[(size_t)g * Cc + lane] = o;
  }
}

extern "C" void kernel_launch(void* const* d_in, const int* in_sizes, int n_in,
                              void* d_out, int out_size, void* d_ws, size_t ws_size,
                              hipStream_t stream)
{
  const float* x     = (const float*)d_in[0];
  const int*   ei    = (const int*)d_in[1];   // [2, E] (int32 from harness)
  const int*   et    = (const int*)d_in[2];   // [E]
  const int*   batch = (const int*)d_in[3];   // [N]
  const float* selfW = (const float*)d_in[4];
  const float* selfb = (const float*)d_in[5];
  const float* eps   = (const float*)d_in[6];
  const float* W1    = (const float*)d_in[7];
  const float* b1    = (const float*)d_in[8];
  const float* W2    = (const float*)d_in[9];
  const float* b2    = (const float*)d_in[10];
  const float* l1W   = (const float*)d_in[11];
  const float* l1b   = (const float*)d_in[12];
  const float* l2W   = (const float*)d_in[13];
  const float* l2b   = (const float*)d_in[14];
  float* out = (float*)d_out;

  // workspace layout (floats): buf0[N*D] buf1[N*D] agg[2*N*D] sums[G*D] cnts[G]
  float* buf0 = (float*)d_ws;
  float* buf1 = buf0 + (size_t)Nn * Dd;
  float* agg  = buf1 + (size_t)Nn * Dd;
  float* sums = agg + (size_t)2 * Nn * Dd;
  float* cnts = sums + (size_t)Gg * Dd;

  const int* src = ei;
  const int* dst = ei + Ee;

  hipMemcpyAsync(buf0, x, (size_t)Nn * Dd * sizeof(float),
                 hipMemcpyDeviceToDevice, stream);
  hipMemsetAsync(sums, 0, (size_t)(Gg * Dd + Gg) * sizeof(float), stream);

  float* h  = buf0;
  float* hn = buf1;
  for (int l = 0; l < Ll; ++l) {
    hipMemsetAsync(agg, 0, (size_t)2 * Nn * Dd * sizeof(float), stream);
    k_scatter<<<(Ee + 3) / 4, 256, 0, stream>>>(h, src, dst, et, agg);
    k_update<<<1024, 512, 0, stream>>>(h, agg, selfW, selfb, eps,
                                       W1, b1, W2, b2, hn, l);
    float* tmp = h; h = hn; hn = tmp;
  }
  k_pool<<<(Nn + 3) / 4, 256, 0, stream>>>(h, batch, sums, cnts);
  k_head<<<1, 256, 0, stream>>>(sums, cnts, l1W, l1b, l2W, l2b, out);
}

// Round 2
// 790.240 us; speedup vs baseline: 2.0550x; 2.0550x over previous
//
#include <hip/hip_runtime.h>

#define Nn 50000
#define Dd 64
#define Ee 800000
#define Ll 3
#define Rr 2
#define Gg 128
#define Cc 10

typedef __attribute__((ext_vector_type(8))) short short8;
typedef __attribute__((ext_vector_type(4))) float f32x4;

__device__ __forceinline__ unsigned short bf16_rne(float x) {
  unsigned u = __float_as_uint(x);
  unsigned r = u + 0x7fffu + ((u >> 16) & 1u);
  return (unsigned short)(r >> 16);
}
__device__ __forceinline__ float bf16_tof(unsigned short b) {
  return __uint_as_float(((unsigned)b) << 16);
}

// ---------------- scatter: per-edge relation-masked aggregation -------------
__global__ __launch_bounds__(256) void k_scatter(
    const float* __restrict__ h, const int* __restrict__ src,
    const int* __restrict__ dst, const int* __restrict__ et,
    float* __restrict__ agg)
{
  int e = blockIdx.x * 4 + (threadIdx.x >> 6);
  if (e >= Ee) return;
  int lane = threadIdx.x & 63;
  int s = src[e];
  int d = dst[e];
  int t = et[e];
  float v = h[(size_t)s * Dd + lane];
  atomicAdd(&agg[((size_t)t * Nn + (size_t)d) * Dd + lane], v);
}

// ---------------- weight prep: W -> W^T split-bf16 (hi/lo) ------------------
// wt layout: [(l*5+m)][c][k] bf16 bits; m: 0=self, 1=W1_r0, 2=W2_r0, 3=W1_r1, 4=W2_r1
__global__ __launch_bounds__(256) void k_prep(
    const float* __restrict__ selfW, const float* __restrict__ W1,
    const float* __restrict__ W2, unsigned short* __restrict__ wtHi,
    unsigned short* __restrict__ wtLo)
{
  int i = blockIdx.x * 256 + threadIdx.x;
  if (i >= Ll * 5 * 4096) return;
  int l = i / (5 * 4096);
  int rem = i - l * 5 * 4096;
  int m = rem >> 12;
  int e = rem & 4095;
  int k = e >> 6, c = e & 63;
  const float* p;
  if (m == 0)      p = selfW + (size_t)l * 4096;
  else if (m == 1) p = W1 + ((size_t)l * 2 + 0) * 4096;
  else if (m == 2) p = W2 + ((size_t)l * 2 + 0) * 4096;
  else if (m == 3) p = W1 + ((size_t)l * 2 + 1) * 4096;
  else             p = W2 + ((size_t)l * 2 + 1) * 4096;
  float w = p[e];
  unsigned short hi = bf16_rne(w);
  unsigned short lo = bf16_rne(w - bf16_tof(hi));
  size_t o = ((size_t)(l * 5 + m) * 64 + c) * 64 + k;
  wtHi[o] = hi;
  wtLo[o] = lo;
}

// ---------------- fused per-layer update via split-bf16 MFMA ----------------
// wave handles 16 nodes; A-frags from global h/agg, B-frags from wt (L2),
// relu intermediate bounced through per-wave LDS for the layout transpose.
#define WOFF(m, c, ks) ((size_t)(m)*4096 + (size_t)(c)*64 + (ks)*32 + koff)

__global__ __launch_bounds__(256) void k_update(
    const float* __restrict__ h, const float* __restrict__ agg,
    const unsigned short* __restrict__ wtHi, const unsigned short* __restrict__ wtLo,
    const float* __restrict__ selfb, const float* __restrict__ eps,
    const float* __restrict__ b1, const float* __restrict__ b2,
    float* __restrict__ hn, int l)
{
  __shared__ __align__(16) unsigned short tbh[4][16 * 72];
  __shared__ __align__(16) unsigned short tbl[4][16 * 72];
  int wave = threadIdx.x >> 6;
  int lane = threadIdx.x & 63;
  int task = blockIdx.x * 4 + wave;
  if (task >= Nn / 16) return;          // 3125 tasks, no barriers anywhere
  int idx15 = lane & 15;
  int kg = lane >> 4;
  int koff = kg * 8;
  size_t nodeA = (size_t)task * 16 + idx15;

  // h row fragment (row = idx15, k = koff..koff+7 per kstep)
  float f[2][8];
#pragma unroll
  for (int ks = 0; ks < 2; ++ks) {
    const float4 a = *(const float4*)&h[nodeA * 64 + ks * 32 + koff];
    const float4 b = *(const float4*)&h[nodeA * 64 + ks * 32 + koff + 4];
    f[ks][0] = a.x; f[ks][1] = a.y; f[ks][2] = a.z; f[ks][3] = a.w;
    f[ks][4] = b.x; f[ks][5] = b.y; f[ks][6] = b.z; f[ks][7] = b.w;
  }
  short8 ahi[2], alo[2];
#pragma unroll
  for (int ks = 0; ks < 2; ++ks)
#pragma unroll
    for (int j = 0; j < 8; ++j) {
      unsigned short hb = bf16_rne(f[ks][j]);
      ahi[ks][j] = (short)hb;
      alo[ks][j] = (short)bf16_rne(f[ks][j] - bf16_tof(hb));
    }

  const unsigned short* whi = wtHi + (size_t)l * 5 * 4096;
  const unsigned short* wlo = wtLo + (size_t)l * 5 * 4096;

  f32x4 facc[4];
#pragma unroll
  for (int cb = 0; cb < 4; ++cb) {
    int c = cb * 16 + idx15;
    float bi = selfb[l * 64 + c] + b2[((size_t)l * 2 + 0) * 64 + c] +
               b2[((size_t)l * 2 + 1) * 64 + c];
    facc[cb] = (f32x4){bi, bi, bi, bi};
  }
  // self GEMM (m = 0)
#pragma unroll
  for (int cb = 0; cb < 4; ++cb) {
    int c = cb * 16 + idx15;
#pragma unroll
    for (int ks = 0; ks < 2; ++ks) {
      const short8 bh = *(const short8*)&whi[WOFF(0, c, ks)];
      const short8 bl = *(const short8*)&wlo[WOFF(0, c, ks)];
      facc[cb] = __builtin_amdgcn_mfma_f32_16x16x32_bf16(ahi[ks], bh, facc[cb], 0, 0, 0);
      facc[cb] = __builtin_amdgcn_mfma_f32_16x16x32_bf16(ahi[ks], bl, facc[cb], 0, 0, 0);
      facc[cb] = __builtin_amdgcn_mfma_f32_16x16x32_bf16(alo[ks], bh, facc[cb], 0, 0, 0);
    }
  }

#pragma unroll
  for (int r = 0; r < Rr; ++r) {
    const int m1 = 1 + 2 * r, m2 = 2 + 2 * r;
    float er = 1.0f + eps[l * Rr + r];
    short8 zhi[2], zlo[2];
#pragma unroll
    for (int ks = 0; ks < 2; ++ks) {
      const float4 a = *(const float4*)&agg[((size_t)r * Nn + nodeA) * 64 + ks * 32 + koff];
      const float4 b = *(const float4*)&agg[((size_t)r * Nn + nodeA) * 64 + ks * 32 + koff + 4];
      float zf[8];
      zf[0] = er * f[ks][0] + a.x; zf[1] = er * f[ks][1] + a.y;
      zf[2] = er * f[ks][2] + a.z; zf[3] = er * f[ks][3] + a.w;
      zf[4] = er * f[ks][4] + b.x; zf[5] = er * f[ks][5] + b.y;
      zf[6] = er * f[ks][6] + b.z; zf[7] = er * f[ks][7] + b.w;
#pragma unroll
      for (int j = 0; j < 8; ++j) {
        unsigned short hb = bf16_rne(zf[j]);
        zhi[ks][j] = (short)hb;
        zlo[ks][j] = (short)bf16_rne(zf[j] - bf16_tof(hb));
      }
    }
    f32x4 tacc[4];
#pragma unroll
    for (int cb = 0; cb < 4; ++cb) {
      float bi = b1[((size_t)l * 2 + r) * 64 + cb * 16 + idx15];
      tacc[cb] = (f32x4){bi, bi, bi, bi};
    }
#pragma unroll
    for (int cb = 0; cb < 4; ++cb) {
      int c = cb * 16 + idx15;
#pragma unroll
      for (int ks = 0; ks < 2; ++ks) {
        const short8 bh = *(const short8*)&whi[WOFF(m1, c, ks)];
        const short8 bl = *(const short8*)&wlo[WOFF(m1, c, ks)];
        tacc[cb] = __builtin_amdgcn_mfma_f32_16x16x32_bf16(zhi[ks], bh, tacc[cb], 0, 0, 0);
        tacc[cb] = __builtin_amdgcn_mfma_f32_16x16x32_bf16(zhi[ks], bl, tacc[cb], 0, 0, 0);
        tacc[cb] = __builtin_amdgcn_mfma_f32_16x16x32_bf16(zlo[ks], bh, tacc[cb], 0, 0, 0);
      }
    }
    // relu -> split-bf16 -> LDS (C-layout row = kg*4+q, col = cb*16+idx15)
#pragma unroll
    for (int cb = 0; cb < 4; ++cb)
#pragma unroll
      for (int q = 0; q < 4; ++q) {
        float tv = fmaxf(tacc[cb][q], 0.0f);
        unsigned short hb = bf16_rne(tv);
        tbh[wave][(kg * 4 + q) * 72 + cb * 16 + idx15] = hb;
        tbl[wave][(kg * 4 + q) * 72 + cb * 16 + idx15] = bf16_rne(tv - bf16_tof(hb));
      }
    asm volatile("s_waitcnt lgkmcnt(0)" ::: "memory");
    __builtin_amdgcn_sched_barrier(0);
    short8 thi[2], tlo[2];
#pragma unroll
    for (int ks = 0; ks < 2; ++ks) {
      thi[ks] = *(const short8*)&tbh[wave][idx15 * 72 + ks * 32 + koff];
      tlo[ks] = *(const short8*)&tbl[wave][idx15 * 72 + ks * 32 + koff];
    }
#pragma unroll
    for (int cb = 0; cb < 4; ++cb) {
      int c = cb * 16 + idx15;
#pragma unroll
      for (int ks = 0; ks < 2; ++ks) {
        const short8 bh = *(const short8*)&whi[WOFF(m2, c, ks)];
        const short8 bl = *(const short8*)&wlo[WOFF(m2, c, ks)];
        facc[cb] = __builtin_amdgcn_mfma_f32_16x16x32_bf16(thi[ks], bh, facc[cb], 0, 0, 0);
        facc[cb] = __builtin_amdgcn_mfma_f32_16x16x32_bf16(thi[ks], bl, facc[cb], 0, 0, 0);
        facc[cb] = __builtin_amdgcn_mfma_f32_16x16x32_bf16(tlo[ks], bh, facc[cb], 0, 0, 0);
      }
    }
  }
#pragma unroll
  for (int cb = 0; cb < 4; ++cb)
#pragma unroll
    for (int q = 0; q < 4; ++q)
      hn[((size_t)task * 16 + kg * 4 + q) * 64 + cb * 16 + idx15] = facc[cb][q];
}

// ---------------- global mean pool: segmented reduction (batch is sorted) ---
__global__ __launch_bounds__(256) void k_pool(
    const float* __restrict__ h, const int* __restrict__ batch,
    float* __restrict__ sums, float* __restrict__ cnts)
{
  int w = blockIdx.x * 4 + (threadIdx.x >> 6);
  int lane = threadIdx.x & 63;
  int start = w * 64;
  if (start >= Nn) return;
  int cnt = min(64, Nn - start);
  int bg = batch[min(start + lane, Nn - 1)];
  int cur = __shfl(bg, 0, 64);
  float acc = 0.0f;
  int run = 0;
  for (int i = 0; i < cnt; ++i) {
    int g = __shfl(bg, i, 64);
    float v = h[(size_t)(start + i) * 64 + lane];
    if (g != cur) {
      atomicAdd(&sums[(size_t)cur * 64 + lane], acc);
      if (lane == 0) atomicAdd(&cnts[cur], (float)run);
      acc = 0.0f; run = 0; cur = g;
    }
    acc += v; run++;
  }
  atomicAdd(&sums[(size_t)cur * 64 + lane], acc);
  if (lane == 0) atomicAdd(&cnts[cur], (float)run);
}

// ---------------- head: pooled -> relu(lin1) -> lin2 ------------------------
__global__ __launch_bounds__(256) void k_head(
    const float* __restrict__ sums, const float* __restrict__ cnts,
    const float* __restrict__ l1W, const float* __restrict__ l1b,
    const float* __restrict__ l2W, const float* __restrict__ l2b,
    float* __restrict__ out)
{
  int wave = threadIdx.x >> 6;
  int lane = threadIdx.x & 63;
  for (int g = wave; g < Gg; g += 4) {
    float p = sums[(size_t)g * Dd + lane] / fmaxf(cnts[g], 1.0f);
    float t = l1b[lane];
#pragma unroll
    for (int k = 0; k < Dd; ++k)
      t += __shfl(p, k, 64) * l1W[k * Dd + lane];
    t = fmaxf(t, 0.0f);
    float o = (lane < Cc) ? l2b[lane] : 0.0f;
#pragma unroll
    for (int k = 0; k < Dd; ++k) {
      float w = (lane < Cc) ? l2W[k * Cc + lane] : 0.0f;
      o += __shfl(t, k, 64) * w;
    }
    if (lane < Cc) out[(size_t)g * Cc + lane] = o;
  }
}

extern "C" void kernel_launch(void* const* d_in, const int* in_sizes, int n_in,
                              void* d_out, int out_size, void* d_ws, size_t ws_size,
                              hipStream_t stream)
{
  const float* x     = (const float*)d_in[0];
  const int*   ei    = (const int*)d_in[1];
  const int*   et    = (const int*)d_in[2];
  const int*   batch = (const int*)d_in[3];
  const float* selfW = (const float*)d_in[4];
  const float* selfb = (const float*)d_in[5];
  const float* eps   = (const float*)d_in[6];
  const float* W1    = (const float*)d_in[7];
  const float* b1    = (const float*)d_in[8];
  const float* W2    = (const float*)d_in[9];
  const float* b2    = (const float*)d_in[10];
  const float* l1W   = (const float*)d_in[11];
  const float* l1b   = (const float*)d_in[12];
  const float* l2W   = (const float*)d_in[13];
  const float* l2b   = (const float*)d_in[14];
  float* out = (float*)d_out;

  // ws: buf0[N*D] buf1[N*D] agg[2*N*D] sums[G*D] cnts[G] wtHi[15*4096]u16 wtLo
  float* buf0 = (float*)d_ws;
  float* buf1 = buf0 + (size_t)Nn * Dd;
  float* agg  = buf1 + (size_t)Nn * Dd;
  float* sums = agg + (size_t)2 * Nn * Dd;
  float* cnts = sums + (size_t)Gg * Dd;
  unsigned short* wtHi = (unsigned short*)(cnts + Gg);
  unsigned short* wtLo = wtHi + (size_t)Ll * 5 * 4096;

  const int* src = ei;
  const int* dst = ei + Ee;

  hipMemcpyAsync(buf0, x, (size_t)Nn * Dd * sizeof(float),
                 hipMemcpyDeviceToDevice, stream);
  hipMemsetAsync(sums, 0, (size_t)(Gg * Dd + Gg) * sizeof(float), stream);
  k_prep<<<(Ll * 5 * 4096 + 255) / 256, 256, 0, stream>>>(selfW, W1, W2, wtHi, wtLo);

  float* h  = buf0;
  float* hn = buf1;
  for (int l = 0; l < Ll; ++l) {
    hipMemsetAsync(agg, 0, (size_t)2 * Nn * Dd * sizeof(float), stream);
    k_scatter<<<(Ee + 3) / 4, 256, 0, stream>>>(h, src, dst, et, agg);
    k_update<<<(Nn / 16 + 3) / 4, 256, 0, stream>>>(h, agg, wtHi, wtLo, selfb,
                                                    eps, b1, b2, hn, l);
    float* tmp = h; h = hn; hn = tmp;
  }
  k_pool<<<(Nn / 64 + 4) / 4, 256, 0, stream>>>(h, batch, sums, cnts);
  k_head<<<1, 256, 0, stream>>>(sums, cnts, l1W, l1b, l2W, l2b, out);
}

// Round 3
// 429.308 us; speedup vs baseline: 3.7826x; 1.8407x over previous
//
#include <hip/hip_runtime.h>

#define Nn 50000
#define Dd 64
#define Ee 800000
#define Ll 3
#define Rr 2
#define Gg 128
#define Cc 10
#define NR (Nn * Rr)
#define NB ((NR + 1023) / 1024)

typedef __attribute__((ext_vector_type(8))) short short8;
typedef __attribute__((ext_vector_type(4))) float f32x4;

__device__ __forceinline__ unsigned short bf16_rne(float x) {
  unsigned u = __float_as_uint(x);
  unsigned r = u + 0x7fffu + ((u >> 16) & 1u);
  return (unsigned short)(r >> 16);
}
__device__ __forceinline__ float bf16_tof(unsigned short b) {
  return __uint_as_float(((unsigned)b) << 16);
}

// ================= CSR build (once per launch; graph static across layers) ==
__global__ __launch_bounds__(256) void k_hist(
    const int* __restrict__ dst, const int* __restrict__ et,
    int* __restrict__ counts)
{
  int e = blockIdx.x * 256 + threadIdx.x;
  if (e >= Ee) return;
  atomicAdd(&counts[et[e] * Nn + dst[e]], 1);
}

// inclusive scan within 1024-elem blocks -> offs[i+1]; block totals -> btot
__global__ __launch_bounds__(1024) void k_scan1(
    const int* __restrict__ counts, int* __restrict__ offs,
    int* __restrict__ btot)
{
  __shared__ int s[1024];
  int i = blockIdx.x * 1024 + threadIdx.x;
  int v = (i < NR) ? counts[i] : 0;
  s[threadIdx.x] = v;
  __syncthreads();
#pragma unroll
  for (int d = 1; d < 1024; d <<= 1) {
    int t = (threadIdx.x >= d) ? s[threadIdx.x - d] : 0;
    __syncthreads();
    s[threadIdx.x] += t;
    __syncthreads();
  }
  if (i < NR) offs[i + 1] = s[threadIdx.x];
  if (threadIdx.x == 1023) btot[blockIdx.x] = s[1023];
}

// exclusive scan of the NB block totals (single 128-thread block)
__global__ __launch_bounds__(128) void k_scan2(
    const int* __restrict__ btot, int* __restrict__ bscan)
{
  __shared__ int s[128];
  int v = (threadIdx.x < NB) ? btot[threadIdx.x] : 0;
  s[threadIdx.x] = v;
  __syncthreads();
#pragma unroll
  for (int d = 1; d < 128; d <<= 1) {
    int t = (threadIdx.x >= d) ? s[threadIdx.x - d] : 0;
    __syncthreads();
    s[threadIdx.x] += t;
    __syncthreads();
  }
  if (threadIdx.x < NB) bscan[threadIdx.x] = s[threadIdx.x] - v;  // exclusive
}

__global__ __launch_bounds__(1024) void k_scan3(
    const int* __restrict__ counts, const int* __restrict__ bscan,
    int* __restrict__ offs, int* __restrict__ cursor)
{
  int i = blockIdx.x * 1024 + threadIdx.x;
  if (i >= NR) return;
  int o = offs[i + 1] + bscan[blockIdx.x];
  offs[i + 1] = o;
  cursor[i] = o - counts[i];
  if (i == 0) offs[0] = 0;
}

__global__ __launch_bounds__(256) void k_fill(
    const int* __restrict__ src, const int* __restrict__ dst,
    const int* __restrict__ et, int* __restrict__ cursor,
    int* __restrict__ elist)
{
  int e = blockIdx.x * 256 + threadIdx.x;
  if (e >= Ee) return;
  int pos = atomicAdd(&cursor[et[e] * Nn + dst[e]], 1);
  elist[pos] = src[e];
}

// ---------------- weight prep: W -> W^T split-bf16 (hi/lo) ------------------
__global__ __launch_bounds__(256) void k_prep(
    const float* __restrict__ selfW, const float* __restrict__ W1,
    const float* __restrict__ W2, unsigned short* __restrict__ wtHi,
    unsigned short* __restrict__ wtLo)
{
  int i = blockIdx.x * 256 + threadIdx.x;
  if (i >= Ll * 5 * 4096) return;
  int l = i / (5 * 4096);
  int rem = i - l * 5 * 4096;
  int m = rem >> 12;
  int e = rem & 4095;
  int k = e >> 6, c = e & 63;
  const float* p;
  if (m == 0)      p = selfW + (size_t)l * 4096;
  else if (m == 1) p = W1 + ((size_t)l * 2 + 0) * 4096;
  else if (m == 2) p = W2 + ((size_t)l * 2 + 0) * 4096;
  else if (m == 3) p = W1 + ((size_t)l * 2 + 1) * 4096;
  else             p = W2 + ((size_t)l * 2 + 1) * 4096;
  float w = p[e];
  unsigned short hi = bf16_rne(w);
  unsigned short lo = bf16_rne(w - bf16_tof(hi));
  size_t o = ((size_t)(l * 5 + m) * 64 + c) * 64 + k;
  wtHi[o] = hi;
  wtLo[o] = lo;
}

// ============ fused per-layer update: CSR gather + split-bf16 MFMA ==========
#define WOFF(m, c, ks) ((size_t)(m)*4096 + (size_t)(c)*64 + (ks)*32 + koff)

__global__ __launch_bounds__(256) void k_update(
    const float* __restrict__ h, const int* __restrict__ offs,
    const int* __restrict__ elist,
    const unsigned short* __restrict__ wtHi, const unsigned short* __restrict__ wtLo,
    const float* __restrict__ selfb, const float* __restrict__ eps,
    const float* __restrict__ b1, const float* __restrict__ b2,
    float* __restrict__ hn, int l)
{
  __shared__ __align__(16) unsigned short tbh[4][16 * 72];
  __shared__ __align__(16) unsigned short tbl[4][16 * 72];
  int wave = threadIdx.x >> 6;
  int lane = threadIdx.x & 63;
  int task = blockIdx.x * 4 + wave;
  if (task >= Nn / 16) return;          // 3125 tasks, no barriers anywhere
  int idx15 = lane & 15;
  int kg = lane >> 4;
  int koff = kg * 8;
  int nodeA = task * 16 + idx15;

  // h row fragment (row = idx15, features koff..koff+7 per kstep)
  float f[2][8];
  {
    const float* hp = &h[(size_t)nodeA * 64 + koff];
    const float4 a0 = *(const float4*)(hp);
    const float4 a1 = *(const float4*)(hp + 4);
    const float4 b0 = *(const float4*)(hp + 32);
    const float4 b1v = *(const float4*)(hp + 36);
    f[0][0] = a0.x; f[0][1] = a0.y; f[0][2] = a0.z; f[0][3] = a0.w;
    f[0][4] = a1.x; f[0][5] = a1.y; f[0][6] = a1.z; f[0][7] = a1.w;
    f[1][0] = b0.x; f[1][1] = b0.y; f[1][2] = b0.z; f[1][3] = b0.w;
    f[1][4] = b1v.x; f[1][5] = b1v.y; f[1][6] = b1v.z; f[1][7] = b1v.w;
  }
  short8 ahi[2], alo[2];
#pragma unroll
  for (int ks = 0; ks < 2; ++ks)
#pragma unroll
    for (int j = 0; j < 8; ++j) {
      unsigned short hb = bf16_rne(f[ks][j]);
      ahi[ks][j] = (short)hb;
      alo[ks][j] = (short)bf16_rne(f[ks][j] - bf16_tof(hb));
    }

  const unsigned short* whi = wtHi + (size_t)l * 5 * 4096;
  const unsigned short* wlo = wtLo + (size_t)l * 5 * 4096;

  f32x4 facc[4];
#pragma unroll
  for (int cb = 0; cb < 4; ++cb) {
    int c = cb * 16 + idx15;
    float bi = selfb[l * 64 + c] + b2[((size_t)l * 2 + 0) * 64 + c] +
               b2[((size_t)l * 2 + 1) * 64 + c];
    facc[cb] = (f32x4){bi, bi, bi, bi};
  }
  // self GEMM (m = 0)
#pragma unroll
  for (int cb = 0; cb < 4; ++cb) {
    int c = cb * 16 + idx15;
#pragma unroll
    for (int ks = 0; ks < 2; ++ks) {
      const short8 bh = *(const short8*)&whi[WOFF(0, c, ks)];
      const short8 bl = *(const short8*)&wlo[WOFF(0, c, ks)];
      facc[cb] = __builtin_amdgcn_mfma_f32_16x16x32_bf16(ahi[ks], bh, facc[cb], 0, 0, 0);
      facc[cb] = __builtin_amdgcn_mfma_f32_16x16x32_bf16(ahi[ks], bl, facc[cb], 0, 0, 0);
      facc[cb] = __builtin_amdgcn_mfma_f32_16x16x32_bf16(alo[ks], bh, facc[cb], 0, 0, 0);
    }
  }

#pragma unroll
  for (int r = 0; r < Rr; ++r) {
    const int m1 = 1 + 2 * r, m2 = 2 + 2 * r;
    float er = 1.0f + eps[l * Rr + r];

    // CSR gather: sum of h[src] rows for this node's feature slice
    float za[2][8];
#pragma unroll
    for (int ks = 0; ks < 2; ++ks)
#pragma unroll
      for (int j = 0; j < 8; ++j) za[ks][j] = 0.0f;
    {
      int aidx = r * Nn + nodeA;
      int jb = offs[aidx], je = offs[aidx + 1];
      for (int j = jb; j < je; ++j) {
        int sn = elist[j];
        const float* hp = &h[(size_t)sn * 64 + koff];
        const float4 a0 = *(const float4*)(hp);
        const float4 a1 = *(const float4*)(hp + 4);
        const float4 b0 = *(const float4*)(hp + 32);
        const float4 b1v = *(const float4*)(hp + 36);
        za[0][0] += a0.x; za[0][1] += a0.y; za[0][2] += a0.z; za[0][3] += a0.w;
        za[0][4] += a1.x; za[0][5] += a1.y; za[0][6] += a1.z; za[0][7] += a1.w;
        za[1][0] += b0.x; za[1][1] += b0.y; za[1][2] += b0.z; za[1][3] += b0.w;
        za[1][4] += b1v.x; za[1][5] += b1v.y; za[1][6] += b1v.z; za[1][7] += b1v.w;
      }
    }

    short8 zhi[2], zlo[2];
#pragma unroll
    for (int ks = 0; ks < 2; ++ks)
#pragma unroll
      for (int j = 0; j < 8; ++j) {
        float zf = er * f[ks][j] + za[ks][j];
        unsigned short hb = bf16_rne(zf);
        zhi[ks][j] = (short)hb;
        zlo[ks][j] = (short)bf16_rne(zf - bf16_tof(hb));
      }

    f32x4 tacc[4];
#pragma unroll
    for (int cb = 0; cb < 4; ++cb) {
      float bi = b1[((size_t)l * 2 + r) * 64 + cb * 16 + idx15];
      tacc[cb] = (f32x4){bi, bi, bi, bi};
    }
#pragma unroll
    for (int cb = 0; cb < 4; ++cb) {
      int c = cb * 16 + idx15;
#pragma unroll
      for (int ks = 0; ks < 2; ++ks) {
        const short8 bh = *(const short8*)&whi[WOFF(m1, c, ks)];
        const short8 bl = *(const short8*)&wlo[WOFF(m1, c, ks)];
        tacc[cb] = __builtin_amdgcn_mfma_f32_16x16x32_bf16(zhi[ks], bh, tacc[cb], 0, 0, 0);
        tacc[cb] = __builtin_amdgcn_mfma_f32_16x16x32_bf16(zhi[ks], bl, tacc[cb], 0, 0, 0);
        tacc[cb] = __builtin_amdgcn_mfma_f32_16x16x32_bf16(zlo[ks], bh, tacc[cb], 0, 0, 0);
      }
    }
    // relu -> split-bf16 -> LDS transpose bounce (per-wave buffer, no barrier)
#pragma unroll
    for (int cb = 0; cb < 4; ++cb)
#pragma unroll
      for (int q = 0; q < 4; ++q) {
        float tv = fmaxf(tacc[cb][q], 0.0f);
        unsigned short hb = bf16_rne(tv);
        tbh[wave][(kg * 4 + q) * 72 + cb * 16 + idx15] = hb;
        tbl[wave][(kg * 4 + q) * 72 + cb * 16 + idx15] = bf16_rne(tv - bf16_tof(hb));
      }
    asm volatile("s_waitcnt lgkmcnt(0)" ::: "memory");
    __builtin_amdgcn_sched_barrier(0);
    short8 thi[2], tlo[2];
#pragma unroll
    for (int ks = 0; ks < 2; ++ks) {
      thi[ks] = *(const short8*)&tbh[wave][idx15 * 72 + ks * 32 + koff];
      tlo[ks] = *(const short8*)&tbl[wave][idx15 * 72 + ks * 32 + koff];
    }
#pragma unroll
    for (int cb = 0; cb < 4; ++cb) {
      int c = cb * 16 + idx15;
#pragma unroll
      for (int ks = 0; ks < 2; ++ks) {
        const short8 bh = *(const short8*)&whi[WOFF(m2, c, ks)];
        const short8 bl = *(const short8*)&wlo[WOFF(m2, c, ks)];
        facc[cb] = __builtin_amdgcn_mfma_f32_16x16x32_bf16(thi[ks], bh, facc[cb], 0, 0, 0);
        facc[cb] = __builtin_amdgcn_mfma_f32_16x16x32_bf16(thi[ks], bl, facc[cb], 0, 0, 0);
        facc[cb] = __builtin_amdgcn_mfma_f32_16x16x32_bf16(tlo[ks], bh, facc[cb], 0, 0, 0);
      }
    }
  }
#pragma unroll
  for (int cb = 0; cb < 4; ++cb)
#pragma unroll
    for (int q = 0; q < 4; ++q)
      hn[((size_t)task * 16 + kg * 4 + q) * 64 + cb * 16 + idx15] = facc[cb][q];
}

// ---------------- global mean pool: segmented reduction (batch is sorted) ---
__global__ __launch_bounds__(256) void k_pool(
    const float* __restrict__ h, const int* __restrict__ batch,
    float* __restrict__ sums, float* __restrict__ cnts)
{
  int w = blockIdx.x * 4 + (threadIdx.x >> 6);
  int lane = threadIdx.x & 63;
  int start = w * 64;
  if (start >= Nn) return;
  int cnt = min(64, Nn - start);
  int bg = batch[min(start + lane, Nn - 1)];
  int cur = __shfl(bg, 0, 64);
  float acc = 0.0f;
  int run = 0;
  for (int i = 0; i < cnt; ++i) {
    int g = __shfl(bg, i, 64);
    float v = h[(size_t)(start + i) * 64 + lane];
    if (g != cur) {
      atomicAdd(&sums[(size_t)cur * 64 + lane], acc);
      if (lane == 0) atomicAdd(&cnts[cur], (float)run);
      acc = 0.0f; run = 0; cur = g;
    }
    acc += v; run++;
  }
  atomicAdd(&sums[(size_t)cur * 64 + lane], acc);
  if (lane == 0) atomicAdd(&cnts[cur], (float)run);
}

// ---------------- head: pooled -> relu(lin1) -> lin2 ------------------------
__global__ __launch_bounds__(256) void k_head(
    const float* __restrict__ sums, const float* __restrict__ cnts,
    const float* __restrict__ l1W, const float* __restrict__ l1b,
    const float* __restrict__ l2W, const float* __restrict__ l2b,
    float* __restrict__ out)
{
  int wave = threadIdx.x >> 6;
  int lane = threadIdx.x & 63;
  for (int g = wave; g < Gg; g += 4) {
    float p = sums[(size_t)g * Dd + lane] / fmaxf(cnts[g], 1.0f);
    float t = l1b[lane];
#pragma unroll
    for (int k = 0; k < Dd; ++k)
      t += __shfl(p, k, 64) * l1W[k * Dd + lane];
    t = fmaxf(t, 0.0f);
    float o = (lane < Cc) ? l2b[lane] : 0.0f;
#pragma unroll
    for (int k = 0; k < Dd; ++k) {
      float w = (lane < Cc) ? l2W[k * Cc + lane] : 0.0f;
      o += __shfl(t, k, 64) * w;
    }
    if (lane < Cc) out[(size_t)g * Cc + lane] = o;
  }
}

extern "C" void kernel_launch(void* const* d_in, const int* in_sizes, int n_in,
                              void* d_out, int out_size, void* d_ws, size_t ws_size,
                              hipStream_t stream)
{
  const float* x     = (const float*)d_in[0];
  const int*   ei    = (const int*)d_in[1];
  const int*   et    = (const int*)d_in[2];
  const int*   batch = (const int*)d_in[3];
  const float* selfW = (const float*)d_in[4];
  const float* selfb = (const float*)d_in[5];
  const float* eps   = (const float*)d_in[6];
  const float* W1    = (const float*)d_in[7];
  const float* b1    = (const float*)d_in[8];
  const float* W2    = (const float*)d_in[9];
  const float* b2    = (const float*)d_in[10];
  const float* l1W   = (const float*)d_in[11];
  const float* l1b   = (const float*)d_in[12];
  const float* l2W   = (const float*)d_in[13];
  const float* l2b   = (const float*)d_in[14];
  float* out = (float*)d_out;

  // ws layout (floats unless noted):
  // buf0[N*D] buf1[N*D] sums[G*D] cnts[G]
  // wtHi[15*4096]u16 wtLo[15*4096]u16
  // counts[NR]i32 offs[NR+1]i32 cursor[NR]i32 btot[NB]i32 bscan[NB]i32 elist[E]i32
  float* buf0 = (float*)d_ws;
  float* buf1 = buf0 + (size_t)Nn * Dd;
  float* sums = buf1 + (size_t)Nn * Dd;
  float* cnts = sums + (size_t)Gg * Dd;
  unsigned short* wtHi = (unsigned short*)(cnts + Gg);
  unsigned short* wtLo = wtHi + (size_t)Ll * 5 * 4096;
  int* counts = (int*)(wtLo + (size_t)Ll * 5 * 4096);
  int* offs   = counts + NR;
  int* cursor = offs + NR + 1;
  int* btot   = cursor + NR;
  int* bscan  = btot + NB;
  int* elist  = bscan + NB;

  const int* src = ei;
  const int* dst = ei + Ee;

  hipMemcpyAsync(buf0, x, (size_t)Nn * Dd * sizeof(float),
                 hipMemcpyDeviceToDevice, stream);
  hipMemsetAsync(sums, 0, (size_t)(Gg * Dd + Gg) * sizeof(float), stream);
  hipMemsetAsync(counts, 0, (size_t)NR * sizeof(int), stream);
  k_prep<<<(Ll * 5 * 4096 + 255) / 256, 256, 0, stream>>>(selfW, W1, W2, wtHi, wtLo);

  // CSR build (graph static across layers)
  k_hist<<<(Ee + 255) / 256, 256, 0, stream>>>(dst, et, counts);
  k_scan1<<<NB, 1024, 0, stream>>>(counts, offs, btot);
  k_scan2<<<1, 128, 0, stream>>>(btot, bscan);
  k_scan3<<<NB, 1024, 0, stream>>>(counts, bscan, offs, cursor);
  k_fill<<<(Ee + 255) / 256, 256, 0, stream>>>(src, dst, et, cursor, elist);

  float* h  = buf0;
  float* hn = buf1;
  for (int l = 0; l < Ll; ++l) {
    k_update<<<(Nn / 16 + 3) / 4, 256, 0, stream>>>(h, offs, elist, wtHi, wtLo,
                                                    selfb, eps, b1, b2, hn, l);
    float* tmp = h; h = hn; hn = tmp;
  }
  k_pool<<<(Nn / 64 + 4) / 4, 256, 0, stream>>>(h, batch, sums, cnts);
  k_head<<<1, 256, 0, stream>>>(sums, cnts, l1W, l1b, l2W, l2b, out);
}